// Round 1
// baseline (54671.594 us; speedup 1.0000x reference)
//
#include <hip/hip_runtime.h>
#include <hip/hip_cooperative_groups.h>

namespace cg = cooperative_groups;

#define Bz 32
#define Tz 256
#define Hz 512
#define Nz 5
#define Rz 2
#define Wz 512
#define RWz 1024
#define XD 1536          // H + R*W
#define IFz 2573         // R*W + 3*W + 5*R + 3
#define EPSF 1e-6f
#define NWG 256
#define NT 256
#define NTH (NWG*NT)

// xi field offsets
#define O_KR 0
#define O_BR 1024
#define O_KW 1026
#define O_BW 1538
#define O_E  1539
#define O_V  2051
#define O_FG 2563
#define O_GA 2565
#define O_GW 2566
#define O_PI 2567

__device__ __forceinline__ float sigf(float x){ return 1.0f/(1.0f+expf(-x)); }
__device__ __forceinline__ float splus(float x){ return fmaxf(x,0.0f) + log1pf(expf(-fabsf(x))); }

// dot of a stride-Bz column (x) with a contiguous row (w), length n (n%4==0)
__device__ __forceinline__ float dot_strided(const float* x, const float* w, int n){
  float a0=0.f,a1=0.f,a2=0.f,a3=0.f;
  for (int k=0;k<n;k+=4){
    a0 = fmaf(x[(size_t)(k+0)*Bz], w[k+0], a0);
    a1 = fmaf(x[(size_t)(k+1)*Bz], w[k+1], a1);
    a2 = fmaf(x[(size_t)(k+2)*Bz], w[k+2], a2);
    a3 = fmaf(x[(size_t)(k+3)*Bz], w[k+3], a3);
  }
  return (a0+a1)+(a2+a3);
}

__device__ void memops(int b, int t, const float* xiT,
                       float* Mg, float* ug, float* pg, float* wwg, float* Lg, float* wrg,
                       float* rT)
{
  __shared__ float s_xi[IFz];
  __shared__ float s_M[Nz*Wz];
  __shared__ float s_u[Nz], s_p[Nz], s_ww[Nz], s_a[Nz], s_L[Nz*Nz], s_wr[Rz*Nz];
  __shared__ float s_sc[13]; // 0:br0 1:br1 2:bw 3:fg0 4:fg1 5:ga 6:gw 7..12:pi
  __shared__ float s_m2[Nz], s_dt[Nz], s_d0[Nz], s_d1[Nz];
  __shared__ float s_kw2, s_kr2[2];
  __shared__ float s_fwd[Rz*Nz], s_bwd[Rz*Nz];

  const int tid = threadIdx.x;
  const int wv = tid >> 6, ln = tid & 63;

  for (int f = tid; f < IFz; f += NT) s_xi[f] = xiT[(size_t)f*Bz + b];
  for (int i = tid; i < Nz*Wz; i += NT) s_M[i] = Mg[(size_t)b*Nz*Wz + i];
  if (tid < Nz){ s_u[tid]=ug[b*Nz+tid]; s_p[tid]=pg[b*Nz+tid]; s_ww[tid]=wwg[b*Nz+tid]; }
  if (tid < Nz*Nz) s_L[tid] = Lg[b*Nz*Nz+tid];
  if (tid < Rz*Nz) s_wr[tid] = wrg[b*Rz*Nz+tid];
  __syncthreads();

  if (tid == 0){
    s_sc[0] = 1.0f + splus(s_xi[O_BR+0]);
    s_sc[1] = 1.0f + splus(s_xi[O_BR+1]);
    s_sc[2] = 1.0f + splus(s_xi[O_BW]);
    s_sc[3] = sigf(s_xi[O_FG+0]);
    s_sc[4] = sigf(s_xi[O_FG+1]);
    s_sc[5] = sigf(s_xi[O_GA]);
    s_sc[6] = sigf(s_xi[O_GW]);
    for (int r=0;r<Rz;r++){
      float x0=s_xi[O_PI+r*3+0], x1=s_xi[O_PI+r*3+1], x2=s_xi[O_PI+r*3+2];
      float m = fmaxf(x0,fmaxf(x1,x2));
      float e0=expf(x0-m), e1=expf(x1-m), e2=expf(x2-m);
      float s = e0+e1+e2;
      s_sc[7+r*3+0]=e0/s; s_sc[7+r*3+1]=e1/s; s_sc[7+r*3+2]=e2/s;
    }
  }
  __syncthreads();

  // psi & usage update (uses OLD ww, OLD wr)
  if (tid < Nz){
    float psi = (1.0f - s_sc[3]*s_wr[0*Nz+tid]) * (1.0f - s_sc[4]*s_wr[1*Nz+tid]);
    float uu = s_u[tid], w = s_ww[tid];
    s_u[tid] = (uu + w - uu*w) * psi;
  }

  // cosine(M_old, kw): per-wave fused dot + ||M_n||^2
  for (int n = wv; n < Nz; n += 4){
    float pd=0.f, pm=0.f;
    for (int w = ln; w < Wz; w += 64){
      float kv = s_xi[O_KW+w], mv = s_M[n*Wz+w];
      pd = fmaf(kv,mv,pd); pm = fmaf(mv,mv,pm);
    }
    for (int off=32; off; off>>=1){ pd += __shfl_down(pd,off,64); pm += __shfl_down(pm,off,64); }
    if (ln==0){ s_dt[n]=pd; s_m2[n]=pm; }
  }
  if (wv == 3){
    float p2=0.f;
    for (int w=ln; w<Wz; w+=64){ float kv=s_xi[O_KW+w]; p2=fmaf(kv,kv,p2); }
    for (int off=32; off; off>>=1) p2 += __shfl_down(p2,off,64);
    if (ln==0) s_kw2 = p2;
  }
  __syncthreads();

  if (tid == 0){
    // allocation weights from updated u (stable ascending argsort, N=5)
    float su[Nz]; int idx[Nz];
    for (int i=0;i<Nz;i++){
      float v = EPSF + (1.0f-EPSF)*s_u[i];
      int j=i;
      while (j>0 && su[j-1] > v){ su[j]=su[j-1]; idx[j]=idx[j-1]; j--; }
      su[j]=v; idx[j]=i;
    }
    float cp = 1.0f;
    for (int k=0;k<Nz;k++){ s_a[idx[k]] = (1.0f - su[k])*cp; cp *= su[k]; }
    // content write weights
    float rk = rsqrtf(s_kw2 + EPSF);
    float lg[Nz], mx=-1e30f;
    for (int n=0;n<Nz;n++){ lg[n] = s_sc[2]*s_dt[n]*rk*rsqrtf(s_m2[n]+EPSF); mx=fmaxf(mx,lg[n]); }
    float ssum=0.f;
    for (int n=0;n<Nz;n++){ lg[n]=expf(lg[n]-mx); ssum+=lg[n]; }
    float ga=s_sc[5], gw=s_sc[6];
    for (int n=0;n<Nz;n++){ float cwn = lg[n]/ssum; s_ww[n] = gw*(ga*s_a[n] + (1.0f-ga)*cwn); }
  }
  __syncthreads();

  // memory write
  for (int i = tid; i < Nz*Wz; i += NT){
    int n = i >> 9, w = i & 511;
    float e = sigf(s_xi[O_E+w]);
    float v = s_xi[O_V+w];
    s_M[i] = s_M[i]*(1.0f - s_ww[n]*e) + s_ww[n]*v;
  }
  __syncthreads();

  // link matrix, precedence, fwd/bwd (tiny, serial)
  if (tid == 0){
    float wsum = 0.f;
    for (int n=0;n<Nz;n++) wsum += s_ww[n];
    float Lo[Nz*Nz];
    for (int i=0;i<Nz;i++)
      for (int j=0;j<Nz;j++)
        Lo[i*Nz+j] = (i==j) ? 0.0f : ((1.0f - s_ww[i] - s_ww[j])*s_L[i*Nz+j] + s_ww[i]*s_p[j]);
    for (int i=0;i<Nz*Nz;i++) s_L[i]=Lo[i];
    for (int j=0;j<Nz;j++) s_p[j] = (1.0f-wsum)*s_p[j] + s_ww[j];
    for (int r=0;r<Rz;r++)
      for (int n=0;n<Nz;n++){
        float f=0.f, bb=0.f;
        for (int m=0;m<Nz;m++){ f = fmaf(s_L[n*Nz+m], s_wr[r*Nz+m], f); bb = fmaf(s_L[m*Nz+n], s_wr[r*Nz+m], bb); }
        s_fwd[r*Nz+n]=f; s_bwd[r*Nz+n]=bb;
      }
  }
  __syncthreads();

  // cosine(M_new, kr)
  for (int n = wv; n < Nz; n += 4){
    float pm=0.f,p0=0.f,p1=0.f;
    for (int w=ln; w<Wz; w+=64){
      float mv=s_M[n*Wz+w];
      pm=fmaf(mv,mv,pm);
      p0=fmaf(s_xi[O_KR+w],    mv,p0);
      p1=fmaf(s_xi[O_KR+Wz+w], mv,p1);
    }
    for (int off=32; off; off>>=1){
      pm += __shfl_down(pm,off,64); p0 += __shfl_down(p0,off,64); p1 += __shfl_down(p1,off,64);
    }
    if (ln==0){ s_m2[n]=pm; s_d0[n]=p0; s_d1[n]=p1; }
  }
  if (wv < 2){
    float p2=0.f;
    for (int w=ln; w<Wz; w+=64){ float kv=s_xi[O_KR+wv*Wz+w]; p2=fmaf(kv,kv,p2); }
    for (int off=32; off; off>>=1) p2 += __shfl_down(p2,off,64);
    if (ln==0) s_kr2[wv]=p2;
  }
  __syncthreads();

  if (tid == 0){
    for (int r=0;r<Rz;r++){
      float rk = rsqrtf(s_kr2[r]+EPSF);
      const float* dd = (r==0) ? s_d0 : s_d1;
      float br = s_sc[r];
      float lg[Nz], mx=-1e30f;
      for (int n=0;n<Nz;n++){ lg[n] = br*dd[n]*rk*rsqrtf(s_m2[n]+EPSF); mx=fmaxf(mx,lg[n]); }
      float ssum=0.f;
      for (int n=0;n<Nz;n++){ lg[n]=expf(lg[n]-mx); ssum+=lg[n]; }
      for (int n=0;n<Nz;n++){
        float crn = lg[n]/ssum;
        s_wr[r*Nz+n] = s_sc[7+r*3+0]*s_bwd[r*Nz+n] + s_sc[7+r*3+1]*crn + s_sc[7+r*3+2]*s_fwd[r*Nz+n];
      }
    }
  }
  __syncthreads();

  // read vectors + state writeback
  float* rdst = rT + (size_t)((t+1)&1)*RWz*Bz;
  for (int w = tid; w < Wz; w += NT){
    float m0=s_M[0*Wz+w], m1=s_M[1*Wz+w], m2=s_M[2*Wz+w], m3=s_M[3*Wz+w], m4=s_M[4*Wz+w];
    for (int r=0;r<Rz;r++){
      float rv = s_wr[r*Nz+0]*m0 + s_wr[r*Nz+1]*m1 + s_wr[r*Nz+2]*m2
               + s_wr[r*Nz+3]*m3 + s_wr[r*Nz+4]*m4;
      rdst[(size_t)(r*Wz+w)*Bz + b] = rv;
    }
  }
  for (int i = tid; i < Nz*Wz; i += NT) Mg[(size_t)b*Nz*Wz+i] = s_M[i];
  if (tid < Nz){ ug[b*Nz+tid]=s_u[tid]; pg[b*Nz+tid]=s_p[tid]; wwg[b*Nz+tid]=s_ww[tid]; }
  if (tid < Nz*Nz) Lg[b*Nz*Nz+tid]=s_L[tid];
  if (tid < Rz*Nz) wrg[b*Rz*Nz+tid]=s_wr[tid];
}

__global__ void __launch_bounds__(NT)
dnc_kernel(const int* src, const float* emb,
           const float* w_ih, const float* w_hh, const float* b_lstm,
           const float* w_xi, const float* b_xi,
           const float* w_out, const float* b_out,
           float* out, float* ws)
{
  cg::grid_group grid = cg::this_grid();
  const int tid = threadIdx.x;
  const int gid = blockIdx.x*NT + tid;

  float* embT  = ws;                                   // [T][H][B]
  float* wxiT  = embT  + (size_t)Tz*Hz*Bz;             // [IF][H]
  float* woutT = wxiT  + (size_t)IFz*Hz;               // [H][XD]
  float* hT    = woutT + (size_t)Hz*XD;                // [2][H][B]
  float* cT    = hT    + 2*Hz*Bz;                      // [H][B]
  float* rT    = cT    + Hz*Bz;                        // [2][RW][B]
  float* xiT   = rT    + 2*RWz*Bz;                     // [IF][B]
  float* Mg    = xiT   + (size_t)IFz*Bz;               // [B][N][W]
  float* ug    = Mg    + (size_t)Bz*Nz*Wz;             // [B][N]
  float* pg    = ug    + Bz*Nz;
  float* wwg   = pg    + Bz*Nz;
  float* Lg    = wwg   + Bz*Nz;                        // [B][N*N]
  float* wrg   = Lg    + Bz*Nz*Nz;                     // [B][R*N]

  // ---- phase 0: init / transposes / embedding gather ----
  for (size_t i = gid; i < (size_t)Tz*Hz*Bz; i += NTH){
    int b = (int)(i & 31); size_t kh = i >> 5;
    int k = (int)(kh & 511); int t = (int)(kh >> 9);
    embT[i] = emb[(size_t)src[b*Tz + t]*Hz + k];
  }
  for (size_t i = gid; i < (size_t)IFz*Hz; i += NTH){
    int k = (int)(i % Hz); size_t f = i / Hz;
    wxiT[i] = w_xi[(size_t)k*IFz + f];
  }
  for (size_t i = gid; i < (size_t)Hz*XD; i += NTH){
    int k = (int)(i % XD); int j = (int)(i / XD);
    woutT[i] = w_out[(size_t)k*Hz + j];
  }
  for (int i = gid; i < 2*Hz*Bz; i += NTH) hT[i]=0.f;
  for (int i = gid; i < Hz*Bz;   i += NTH) cT[i]=0.f;
  for (int i = gid; i < 2*RWz*Bz;i += NTH) rT[i]=0.f;
  for (int i = gid; i < Bz*Nz*Wz;i += NTH) Mg[i]=0.f;
  for (int i = gid; i < Bz*(3*Nz + Nz*Nz + Rz*Nz); i += NTH) ug[i]=0.f; // ug..wrg contiguous
  grid.sync();

  // ---- time loop ----
  for (int t = 0; t < Tz; ++t){
    const int cur = t & 1, nxt = (t+1)&1;

    // Phase A: gates GEMM + LSTM pointwise (shfl-combined 4 gate lanes)
    {
      const int gate = gid & 3;
      const int b    = (gid >> 2) & 31;
      const int j    = gid >> 7;
      const int row  = gate*Hz + j;
      const float* w1 = w_ih + (size_t)row*XD;
      const float* w2 = w_hh + (size_t)row*Hz;
      const float* xc = embT + (size_t)t*Hz*Bz + b;
      const float* rc = rT + (size_t)cur*RWz*Bz + b;
      const float* hc = hT + (size_t)cur*Hz*Bz + b;
      float acc = dot_strided(xc, w1, Hz)
                + dot_strided(rc, w1+Hz, RWz)
                + dot_strided(hc, w2, Hz)
                + b_lstm[row];
      const int lane = tid & 63;
      const int bse  = lane & ~3;
      float gi = __shfl(acc, bse+0, 64);
      float gf = __shfl(acc, bse+1, 64);
      float gg = __shfl(acc, bse+2, 64);
      float go = __shfl(acc, bse+3, 64);
      if (gate == 0){
        float cv = cT[j*Bz+b];
        float cn = sigf(gf)*cv + sigf(gi)*tanhf(gg);
        float hn = sigf(go)*tanhf(cn);
        cT[j*Bz+b] = cn;
        hT[(size_t)nxt*Hz*Bz + j*Bz + b] = hn;
      }
    }
    grid.sync();

    // Phase B: xi = h_new @ w_xi + b_xi
    {
      const float* hbase = hT + (size_t)nxt*Hz*Bz;
      for (int id = gid; id < IFz*Bz; id += NTH){
        const int b = id & 31, f = id >> 5;
        xiT[id] = dot_strided(hbase + b, wxiT + (size_t)f*Hz, Hz) + b_xi[f];
      }
    }
    grid.sync();

    // Phase C: WGs 0..31 do DNC memory ops; WGs 32+ compute out(t-1)
    if (blockIdx.x < Bz){
      memops(blockIdx.x, t, xiT, Mg, ug, pg, wwg, Lg, wrg, rT);
    } else if (t > 0){
      int id = (blockIdx.x - Bz)*NT + tid;
      if (id < Hz*Bz){
        const int b = id & 31, j = id >> 5;
        const float* wj = woutT + (size_t)j*XD;
        float acc = dot_strided(hT + (size_t)cur*Hz*Bz + b, wj, Hz)
                  + dot_strided(rT + (size_t)cur*RWz*Bz + b, wj+Hz, RWz)
                  + b_out[j];
        out[(size_t)b*Tz*Hz + (size_t)(t-1)*Hz + j] = acc;
      }
    }
    grid.sync();
  }

  // ---- epilogue: out(T-1), final h and c ----
  if (gid < Hz*Bz){
    const int b = gid & 31, j = gid >> 5;
    const float* wj = woutT + (size_t)j*XD;
    float acc = dot_strided(hT + b, wj, Hz)          // h(255) in hT[0]
              + dot_strided(rT + b, wj+Hz, RWz)      // r(255) in rT[0]
              + b_out[j];
    out[(size_t)b*Tz*Hz + (size_t)(Tz-1)*Hz + j] = acc;
    out[(size_t)Bz*Tz*Hz + (size_t)b*Hz + j]          = hT[j*Bz+b];
    out[(size_t)Bz*Tz*Hz + (size_t)Bz*Hz + (size_t)b*Hz + j] = cT[j*Bz+b];
  }
}

extern "C" void kernel_launch(void* const* d_in, const int* in_sizes, int n_in,
                              void* d_out, int out_size, void* d_ws, size_t ws_size,
                              hipStream_t stream)
{
  const int*   src    = (const int*)  d_in[0];
  // d_in[1] = source_lengths (unused by reference)
  const float* emb    = (const float*)d_in[2];
  const float* w_ih   = (const float*)d_in[3];
  const float* w_hh   = (const float*)d_in[4];
  const float* b_lstm = (const float*)d_in[5];
  const float* w_xi   = (const float*)d_in[6];
  const float* b_xi   = (const float*)d_in[7];
  const float* w_out  = (const float*)d_in[8];
  const float* b_out  = (const float*)d_in[9];
  float* out = (float*)d_out;
  float* ws  = (float*)d_ws;

  void* args[] = { &src, &emb, &w_ih, &w_hh, &b_lstm, &w_xi, &b_xi, &w_out, &b_out, &out, &ws };
  hipLaunchCooperativeKernel((const void*)dnc_kernel, dim3(NWG), dim3(NT), args, 0, stream);
}